// Round 1
// baseline (274.245 us; speedup 1.0000x reference)
//
#include <hip/hip_runtime.h>
#include <hip/hip_bf16.h>

typedef __attribute__((ext_vector_type(8))) short short8;
typedef __attribute__((ext_vector_type(4))) short short4v;
typedef __attribute__((ext_vector_type(4))) float f32x4;

#define SCALE_Q 0.17677669529663687f

__device__ __forceinline__ short f2bf(float f) {
  union { float f; unsigned u; } v; v.f = f;
  unsigned r = (v.u + 0x7fffu + ((v.u >> 16) & 1u)) >> 16;
  return (short)r;
}

// ---------------------------------------------------------------------------
// K1: qkv = x @ qkv_w^T + qkv_b  (bf16 MFMA, fp32 acc); scatter to
//     q[b][h][n][d]*SCALE, k[b][h][n][d], vt[b][h][d][n]   (all bf16)
// M = 200704 = 1568*128 exactly, K = 128, N = 384 (3 chunks of 128)
// ---------------------------------------------------------------------------
__global__ __launch_bounds__(256) void k_qkv(
    const float* __restrict__ x, const float* __restrict__ w,
    const float* __restrict__ bias,
    short* __restrict__ qo, short* __restrict__ ko, short* __restrict__ vto)
{
  __shared__ short As[128][136];   // +8 pad: 2-way bank alias (free)
  __shared__ short Ws[128][136];
  const int tid = threadIdx.x;
  const int lane = tid & 63;
  const int wave = tid >> 6;
  const int l15 = lane & 15, grp = lane >> 4;
  const int row0 = blockIdx.x * 128;
  const int wm = (wave >> 1) * 64;
  const int wn = (wave & 1) * 64;

  // stage x tile fp32 -> bf16 (coalesced float4)
  for (int i = 0; i < 16; ++i) {
    int idx = tid + i * 256;
    int r = idx >> 5, c4 = idx & 31;
    float4 v = *reinterpret_cast<const float4*>(&x[(size_t)(row0 + r) * 128 + c4 * 4]);
    short4v s; s[0] = f2bf(v.x); s[1] = f2bf(v.y); s[2] = f2bf(v.z); s[3] = f2bf(v.w);
    *reinterpret_cast<short4v*>(&As[r][c4 * 4]) = s;
  }

  for (int ci = 0; ci < 3; ++ci) {
    __syncthreads();   // protect Ws from previous chunk's readers (and As stage at ci=0)
    for (int i = 0; i < 16; ++i) {
      int idx = tid + i * 256;
      int r = idx >> 5, c4 = idx & 31;
      float4 v = *reinterpret_cast<const float4*>(&w[(size_t)(ci * 128 + r) * 128 + c4 * 4]);
      short4v s; s[0] = f2bf(v.x); s[1] = f2bf(v.y); s[2] = f2bf(v.z); s[3] = f2bf(v.w);
      *reinterpret_cast<short4v*>(&Ws[r][c4 * 4]) = s;
    }
    __syncthreads();

    f32x4 acc[4][4];
    for (int nt = 0; nt < 4; ++nt) {
      float bv = bias[ci * 128 + wn + nt * 16 + l15];
      for (int mt = 0; mt < 4; ++mt) acc[mt][nt] = (f32x4){bv, bv, bv, bv};
    }
    for (int ks = 0; ks < 4; ++ks) {
      int k0 = ks * 32 + grp * 8;
      short8 af[4], bfr[4];
      for (int mt = 0; mt < 4; ++mt)
        af[mt] = *reinterpret_cast<const short8*>(&As[wm + mt * 16 + l15][k0]);
      for (int nt = 0; nt < 4; ++nt)
        bfr[nt] = *reinterpret_cast<const short8*>(&Ws[wn + nt * 16 + l15][k0]);
      for (int mt = 0; mt < 4; ++mt)
        for (int nt = 0; nt < 4; ++nt)
          acc[mt][nt] = __builtin_amdgcn_mfma_f32_16x16x32_bf16(af[mt], bfr[nt], acc[mt][nt], 0, 0, 0);
    }

    const float scl = (ci == 0) ? SCALE_Q : 1.0f;
    for (int mt = 0; mt < 4; ++mt)
      for (int r = 0; r < 4; ++r) {
        unsigned t = (unsigned)(row0 + wm + mt * 16 + grp * 4 + r);
        unsigned b = t / 49u;           // compiler magic-mul
        unsigned n = t - b * 49u;
        for (int nt = 0; nt < 4; ++nt) {
          int cc = wn + nt * 16 + l15;
          int h = cc >> 5, d = cc & 31;
          short val = f2bf(acc[mt][nt][r] * scl);
          if (ci == 0)      qo[((size_t)(b * 4 + h) * 49 + n) * 32 + d] = val;
          else if (ci == 1) ko[((size_t)(b * 4 + h) * 49 + n) * 32 + d] = val;
          else              vto[((size_t)(b * 4 + h) * 32 + d) * 49 + n] = val;
        }
      }
  }
}

// ---------------------------------------------------------------------------
// K2: fused window attention. One wave per (b,h). 49 padded to 64.
//     logits = q@k^T (+rpb +mask), softmax over keys, out = P@V (bf16 MFMA).
// ---------------------------------------------------------------------------
__global__ __launch_bounds__(256) void k_attn(
    const short* __restrict__ q, const short* __restrict__ k,
    const short* __restrict__ vt, const float* __restrict__ mask,
    const float* __restrict__ rpb, short* __restrict__ ao)
{
  __shared__ short P[4][64][72];   // per-wave P tile, stride 72 (2-way alias)
  __shared__ short V[4][32][72];   // per-wave V^T tile, zero-padded to 64 keys
  const int tid = threadIdx.x;
  const int lane = tid & 63;
  const int wv = tid >> 6;
  const int bh = blockIdx.x * 4 + wv;
  const int b = bh >> 2, h = bh & 3;
  const int wdx = b & 63;          // b % NW
  const int l15 = lane & 15, grp = lane >> 4;
  const int k0 = grp * 8;

  // ---- stage V^T (32 x 49 bf16, contiguous 3136B) into padded LDS ----
  {
    short* vbase = &V[wv][0][0];
    short4v z4 = (short4v){0, 0, 0, 0};
    for (int i = 0; i < 9; ++i)                       // zero 32*72 shorts
      *reinterpret_cast<short4v*>(vbase + (lane + i * 64) * 4) = z4;
    for (int i = 0; i < 7; ++i) {
      int idx = lane + i * 64;                        // 392 short4 chunks
      if (idx < 392) {
        short4v s = *reinterpret_cast<const short4v*>(&vt[(size_t)bh * 1568 + idx * 4]);
        int f = idx * 4;
        for (int e = 0; e < 4; ++e) {
          int fe = f + e;
          int d = fe / 49;                            // compiler magic
          int kk = fe - d * 49;
          V[wv][d][kk] = s[e];
        }
      }
    }
  }

  // ---- QK^T: direct global fragment loads (rows are 64B, 16B-aligned) ----
  short8 zf = (short8){0, 0, 0, 0, 0, 0, 0, 0};
  short8 af[4], bfr[4];
  for (int mt = 0; mt < 4; ++mt) {
    int m = mt * 16 + l15;
    af[mt] = zf;
    if (m < 49) af[mt] = *reinterpret_cast<const short8*>(&q[((size_t)bh * 49 + m) * 32 + k0]);
  }
  for (int nt = 0; nt < 4; ++nt) {
    int n = nt * 16 + l15;
    bfr[nt] = zf;
    if (n < 49) bfr[nt] = *reinterpret_cast<const short8*>(&k[((size_t)bh * 49 + n) * 32 + k0]);
  }
  f32x4 att[4][4];
  for (int mt = 0; mt < 4; ++mt)
    for (int nt = 0; nt < 4; ++nt) att[mt][nt] = (f32x4){0, 0, 0, 0};
  for (int mt = 0; mt < 4; ++mt)
    for (int nt = 0; nt < 4; ++nt)
      att[mt][nt] = __builtin_amdgcn_mfma_f32_16x16x32_bf16(af[mt], bfr[nt], att[mt][nt], 0, 0, 0);

  // ---- add relative-position bias + window mask; -inf at padded keys ----
  for (int mt = 0; mt < 4; ++mt)
    for (int r = 0; r < 4; ++r) {
      int m = mt * 16 + grp * 4 + r;
      if (m < 49) {
        int mi = (m * 37) >> 8;       // m / 7 for m < 49
        int mj = m - mi * 7;
        for (int nt = 0; nt < 4; ++nt) {
          int n = nt * 16 + l15;
          if (n < 49) {
            int ni = (n * 37) >> 8;
            int nj = n - ni * 7;
            int ridx = (mi - ni + 6) * 13 + (mj - nj + 6);
            att[mt][nt][r] += rpb[ridx * 4 + h] + mask[((size_t)wdx * 49 + m) * 49 + n];
          } else {
            att[mt][nt][r] = -1e30f;
          }
        }
      }
      // m >= 49: leave logits (0 at n<49) — rows never stored, stay finite
    }

  // ---- softmax over keys: 4 local + 16-lane butterfly; defer 1/sum ----
  float rinv[4][4];
  for (int mt = 0; mt < 4; ++mt)
    for (int r = 0; r < 4; ++r) {
      float mx = fmaxf(fmaxf(att[mt][0][r], att[mt][1][r]),
                       fmaxf(att[mt][2][r], att[mt][3][r]));
      for (int d = 1; d < 16; d <<= 1) mx = fmaxf(mx, __shfl_xor(mx, d));
      float s = 0.f;
      for (int nt = 0; nt < 4; ++nt) {
        float e = __expf(att[mt][nt][r] - mx);
        att[mt][nt][r] = e;
        s += e;
      }
      for (int d = 1; d < 16; d <<= 1) s += __shfl_xor(s, d);
      rinv[mt][r] = 1.0f / s;
    }

  // ---- P -> LDS (bf16) ----
  for (int mt = 0; mt < 4; ++mt)
    for (int nt = 0; nt < 4; ++nt)
      for (int r = 0; r < 4; ++r)
        P[wv][mt * 16 + grp * 4 + r][nt * 16 + l15] = f2bf(att[mt][nt][r]);

  // ---- PV: (64x64)@(64x32) ----
  f32x4 o[4][2];
  for (int mt = 0; mt < 4; ++mt)
    for (int dt = 0; dt < 2; ++dt) o[mt][dt] = (f32x4){0, 0, 0, 0};
  for (int ks = 0; ks < 2; ++ks) {
    short8 pa[4], pb[2];
    for (int mt = 0; mt < 4; ++mt)
      pa[mt] = *reinterpret_cast<const short8*>(&P[wv][mt * 16 + l15][ks * 32 + k0]);
    for (int dt = 0; dt < 2; ++dt)
      pb[dt] = *reinterpret_cast<const short8*>(&V[wv][dt * 16 + l15][ks * 32 + k0]);
    for (int mt = 0; mt < 4; ++mt)
      for (int dt = 0; dt < 2; ++dt)
        o[mt][dt] = __builtin_amdgcn_mfma_f32_16x16x32_bf16(pa[mt], pb[dt], o[mt][dt], 0, 0, 0);
  }

  // ---- epilogue: divide by rowsum, store bf16 attn-out (B,N,C layout) ----
  for (int mt = 0; mt < 4; ++mt)
    for (int r = 0; r < 4; ++r) {
      int m = mt * 16 + grp * 4 + r;
      if (m < 49) {
        size_t base = ((size_t)b * 49 + m) * 128 + h * 32;
        for (int dt = 0; dt < 2; ++dt)
          ao[base + dt * 16 + l15] = f2bf(o[mt][dt][r] * rinv[mt][r]);
      }
    }
}

// ---------------------------------------------------------------------------
// K3: out = attn_out @ proj_w^T + proj_b   (M=200704, N=128, K=128) fp32 out
// ---------------------------------------------------------------------------
__global__ __launch_bounds__(256) void k_proj(
    const short* __restrict__ a, const float* __restrict__ w,
    const float* __restrict__ bias, float* __restrict__ out)
{
  __shared__ short As[128][136];
  __shared__ short Ws[128][136];
  const int tid = threadIdx.x;
  const int lane = tid & 63;
  const int wave = tid >> 6;
  const int l15 = lane & 15, grp = lane >> 4;
  const int row0 = blockIdx.x * 128;
  const int wm = (wave >> 1) * 64;
  const int wn = (wave & 1) * 64;

  for (int i = 0; i < 8; ++i) {      // A tile is already bf16: straight copy
    int idx = tid + i * 256;
    int r = idx >> 4, c8 = idx & 15;
    *reinterpret_cast<short8*>(&As[r][c8 * 8]) =
        *reinterpret_cast<const short8*>(&a[(size_t)(row0 + r) * 128 + c8 * 8]);
  }
  for (int i = 0; i < 16; ++i) {     // W fp32 -> bf16
    int idx = tid + i * 256;
    int r = idx >> 5, c4 = idx & 31;
    float4 v = *reinterpret_cast<const float4*>(&w[(size_t)r * 128 + c4 * 4]);
    short4v s; s[0] = f2bf(v.x); s[1] = f2bf(v.y); s[2] = f2bf(v.z); s[3] = f2bf(v.w);
    *reinterpret_cast<short4v*>(&Ws[r][c4 * 4]) = s;
  }
  __syncthreads();

  f32x4 acc[4][4];
  for (int nt = 0; nt < 4; ++nt) {
    float bv = bias[wn + nt * 16 + l15];
    for (int mt = 0; mt < 4; ++mt) acc[mt][nt] = (f32x4){bv, bv, bv, bv};
  }
  for (int ks = 0; ks < 4; ++ks) {
    int kk0 = ks * 32 + grp * 8;
    short8 af[4], bfr[4];
    for (int mt = 0; mt < 4; ++mt)
      af[mt] = *reinterpret_cast<const short8*>(&As[wm + mt * 16 + l15][kk0]);
    for (int nt = 0; nt < 4; ++nt)
      bfr[nt] = *reinterpret_cast<const short8*>(&Ws[wn + nt * 16 + l15][kk0]);
    for (int mt = 0; mt < 4; ++mt)
      for (int nt = 0; nt < 4; ++nt)
        acc[mt][nt] = __builtin_amdgcn_mfma_f32_16x16x32_bf16(af[mt], bfr[nt], acc[mt][nt], 0, 0, 0);
  }
  for (int mt = 0; mt < 4; ++mt)
    for (int r = 0; r < 4; ++r) {
      size_t t = (size_t)(row0 + wm + mt * 16 + grp * 4 + r);
      for (int nt = 0; nt < 4; ++nt)
        out[t * 128 + wn + nt * 16 + l15] = acc[mt][nt][r];
    }
}

// ---------------------------------------------------------------------------
extern "C" void kernel_launch(void* const* d_in, const int* in_sizes, int n_in,
                              void* d_out, int out_size, void* d_ws, size_t ws_size,
                              hipStream_t stream) {
  const float* x    = (const float*)d_in[0];
  const float* mask = (const float*)d_in[1];
  const float* qkvw = (const float*)d_in[2];
  const float* qkvb = (const float*)d_in[3];
  const float* rpb  = (const float*)d_in[4];
  const float* pw   = (const float*)d_in[5];
  const float* pb   = (const float*)d_in[6];
  float* out = (float*)d_out;

  char* ws = (char*)d_ws;
  short* q  = (short*)(ws);                    // 4096*4*49*32 bf16 = 51,380,224 B
  short* k  = (short*)(ws + 51380224ull);      // same
  short* vt = (short*)(ws + 102760448ull);     // [b][h][d][n] transposed V
  short* ao = (short*)(ws + 154140672ull);     // attn out bf16 (B,N,C)
  // total ws usage: 205,520,896 B

  k_qkv <<<1568, 256, 0, stream>>>(x, qkvw, qkvb, q, k, vt);
  k_attn<<<4096, 256, 0, stream>>>(q, k, vt, mask, rpb, ao);
  k_proj<<<1568, 256, 0, stream>>>(ao, pw, pb, out);
}

// Round 2
// 230.211 us; speedup vs baseline: 1.1913x; 1.1913x over previous
//
#include <hip/hip_runtime.h>
#include <hip/hip_bf16.h>

typedef __attribute__((ext_vector_type(8))) short short8;
typedef __attribute__((ext_vector_type(4))) short short4v;
typedef __attribute__((ext_vector_type(4))) float f32x4;

#define SCALE_Q 0.17677669529663687f

__device__ __forceinline__ short f2bf(float f) {
  union { float f; unsigned u; } v; v.f = f;
  unsigned r = (v.u + 0x7fffu + ((v.u >> 16) & 1u)) >> 16;
  return (short)r;
}

__device__ __forceinline__ short8 pack8(float4 a, float4 b) {
  short8 s;
  s[0] = f2bf(a.x); s[1] = f2bf(a.y); s[2] = f2bf(a.z); s[3] = f2bf(a.w);
  s[4] = f2bf(b.x); s[5] = f2bf(b.y); s[6] = f2bf(b.z); s[7] = f2bf(b.w);
  return s;
}

// ---------------------------------------------------------------------------
// k_prep: (a) combined attention bias table tab[wdx][h][m][n] = mask + rpb
//         (b) qkv_w / proj_w fp32 -> bf16 in ws
// ---------------------------------------------------------------------------
__global__ __launch_bounds__(256) void k_prep(
    const float* __restrict__ mask, const float* __restrict__ rpb,
    const float* __restrict__ qkvw, const float* __restrict__ pw,
    float* __restrict__ tab, short* __restrict__ wbf, short* __restrict__ pwbf)
{
  const int bid = blockIdx.x, tid = threadIdx.x;
  if (bid < 256) {
    const int wdx = bid >> 2, h = bid & 3;
    for (int t = tid; t < 2401; t += 256) {
      unsigned m = (unsigned)t / 49u;
      unsigned n = (unsigned)t - m * 49u;
      int mi = ((int)m * 37) >> 8, mj = (int)m - mi * 7;
      int ni = ((int)n * 37) >> 8, nj = (int)n - ni * 7;
      int ridx = (mi - ni + 6) * 13 + (mj - nj + 6);
      tab[(size_t)bid * 2401 + t] = mask[(size_t)wdx * 2401 + t] + rpb[ridx * 4 + h];
    }
  } else {
    const int j = bid - 256;                   // 0..7
    for (int i = 0; i < 8; ++i) {
      int idx4 = (j * 8 + i) * 256 + tid;      // float4 index, 16384 total
      if (idx4 < 12288) {
        float4 v = *reinterpret_cast<const float4*>(&qkvw[(size_t)idx4 * 4]);
        short4v s; s[0] = f2bf(v.x); s[1] = f2bf(v.y); s[2] = f2bf(v.z); s[3] = f2bf(v.w);
        *reinterpret_cast<short4v*>(&wbf[(size_t)idx4 * 4]) = s;
      } else {
        int r = idx4 - 12288;
        float4 v = *reinterpret_cast<const float4*>(&pw[(size_t)r * 4]);
        short4v s; s[0] = f2bf(v.x); s[1] = f2bf(v.y); s[2] = f2bf(v.z); s[3] = f2bf(v.w);
        *reinterpret_cast<short4v*>(&pwbf[(size_t)r * 4]) = s;
      }
    }
  }
}

// ---------------------------------------------------------------------------
// k_fused: whole WindowMSA per window. 2 windows/block, 4 waves
// (2 waves per window: sub=0 handles rows 0..31, sub=1 rows 32..63(pad)).
// Per head: qkv MFMA -> q,k,Vt LDS -> QK^T -> +bias table -> softmax ->
// P LDS -> PV -> ao LDS -> proj-accumulate.  Out written once, fp32.
// ---------------------------------------------------------------------------
__global__ __launch_bounds__(256, 2) void k_fused(
    const float* __restrict__ x, const float* __restrict__ qkvb,
    const float* __restrict__ pb, const float* __restrict__ tab,
    const short* __restrict__ wbf, const short* __restrict__ pwbf,
    float* __restrict__ out)
{
  __shared__ short QK[2][64][152];   // cols: q 0..31 | k 40..71 | P/ao 80..143
  __shared__ short Vt[2][32][72];    // V transposed: [d][token]
  const int tid = threadIdx.x;
  const int lane = tid & 63;
  const int wv = tid >> 6;           // 0..3
  const int win = wv >> 1;           // 0..1
  const int sub = wv & 1;            // row half
  const int l15 = lane & 15, grp = lane >> 4;
  const int gwin = blockIdx.x * 2 + win;
  const int wdx = gwin & 63;
  const size_t xbase = (size_t)gwin * 49 * 128;

  // ---- x A-fragments in registers (rows >=49 zero), reused for all heads ----
  short8 xf[2][4];
  for (int mt = 0; mt < 2; ++mt) {
    int lr = sub * 32 + mt * 16 + l15;
    bool valid = lr < 49;
    for (int ks = 0; ks < 4; ++ks) {
      short8 f = (short8){0, 0, 0, 0, 0, 0, 0, 0};
      if (valid) {
        const float* p = &x[xbase + (size_t)lr * 128 + ks * 32 + grp * 8];
        float4 a = *reinterpret_cast<const float4*>(p);
        float4 b = *reinterpret_cast<const float4*>(p + 4);
        f = pack8(a, b);
      }
      xf[mt][ks] = f;
    }
  }

  f32x4 pacc[2][8];
  for (int mt = 0; mt < 2; ++mt)
    for (int nt = 0; nt < 8; ++nt) pacc[mt][nt] = (f32x4){0, 0, 0, 0};

  for (int h = 0; h < 4; ++h) {
    // ---- qkv GEMM: M=32(own) x N=96(q,k,v) x K=128; B-frags from L2 ----
    f32x4 acc[2][6];
    for (int nt = 0; nt < 6; ++nt) {
      int brow = (nt >> 1) * 128 + h * 32 + (nt & 1) * 16 + l15;
      float bv = qkvb[brow];
      acc[0][nt] = (f32x4){bv, bv, bv, bv};
      acc[1][nt] = (f32x4){bv, bv, bv, bv};
    }
    for (int ks = 0; ks < 4; ++ks) {
      short8 bfr[6];
      for (int nt = 0; nt < 6; ++nt) {
        int brow = (nt >> 1) * 128 + h * 32 + (nt & 1) * 16 + l15;
        bfr[nt] = *reinterpret_cast<const short8*>(&wbf[(size_t)brow * 128 + ks * 32 + grp * 8]);
      }
      for (int mt = 0; mt < 2; ++mt)
        for (int nt = 0; nt < 6; ++nt)
          acc[mt][nt] = __builtin_amdgcn_mfma_f32_16x16x32_bf16(xf[mt][ks], bfr[nt], acc[mt][nt], 0, 0, 0);
    }
    // ---- write q (scaled), k, Vt to LDS ----
    for (int mt = 0; mt < 2; ++mt)
      for (int r = 0; r < 4; ++r) {
        int lr = sub * 32 + mt * 16 + grp * 4 + r;
        QK[win][lr][l15]      = f2bf(acc[mt][0][r] * SCALE_Q);
        QK[win][lr][16 + l15] = f2bf(acc[mt][1][r] * SCALE_Q);
        QK[win][lr][40 + l15] = f2bf(acc[mt][2][r]);
        QK[win][lr][56 + l15] = f2bf(acc[mt][3][r]);
        Vt[win][l15][lr]      = f2bf(acc[mt][4][r]);
        Vt[win][16 + l15][lr] = f2bf(acc[mt][5][r]);
      }
    __syncthreads();

    // ---- QK^T (K=32, single MFMA k-step) ----
    short8 qa[2], kb[4];
    for (int mt = 0; mt < 2; ++mt)
      qa[mt] = *reinterpret_cast<const short8*>(&QK[win][sub * 32 + mt * 16 + l15][grp * 8]);
    for (int nt = 0; nt < 4; ++nt)
      kb[nt] = *reinterpret_cast<const short8*>(&QK[win][nt * 16 + l15][40 + grp * 8]);
    f32x4 att[2][4];
    for (int mt = 0; mt < 2; ++mt)
      for (int nt = 0; nt < 4; ++nt) att[mt][nt] = (f32x4){0, 0, 0, 0};
    for (int mt = 0; mt < 2; ++mt)
      for (int nt = 0; nt < 4; ++nt)
        att[mt][nt] = __builtin_amdgcn_mfma_f32_16x16x32_bf16(qa[mt], kb[nt], att[mt][nt], 0, 0, 0);

    // ---- bias table + softmax (defer 1/sum); P -> LDS bf16 ----
    float rinv[2][4];
    for (int mt = 0; mt < 2; ++mt)
      for (int r = 0; r < 4; ++r) {
        int m = sub * 32 + mt * 16 + grp * 4 + r;
        const float* trow = &tab[((size_t)(wdx * 4 + h) * 49 + (m < 49 ? m : 0)) * 49];
        float v[4];
        for (int nt = 0; nt < 4; ++nt) {
          int n = nt * 16 + l15;
          v[nt] = (m < 49 && n < 49) ? att[mt][nt][r] + trow[n] : -1e30f;
        }
        float mx = fmaxf(fmaxf(v[0], v[1]), fmaxf(v[2], v[3]));
        for (int d = 1; d < 16; d <<= 1) mx = fmaxf(mx, __shfl_xor(mx, d));
        float s = 0.f;
        for (int nt = 0; nt < 4; ++nt) {
          float e = __expf(v[nt] - mx);
          s += e;
          QK[win][m][80 + nt * 16 + l15] = f2bf(e);
        }
        for (int d = 1; d < 16; d <<= 1) s += __shfl_xor(s, d);
        rinv[mt][r] = 1.0f / s;
      }
    // own rows only written/read below -> no barrier needed here

    // ---- PV: (own 32 x 64keys) @ (64keys x 32d) ----
    short8 pa[2][2], vb[2][2];
    for (int mt = 0; mt < 2; ++mt)
      for (int ks = 0; ks < 2; ++ks)
        pa[mt][ks] = *reinterpret_cast<const short8*>(&QK[win][sub * 32 + mt * 16 + l15][80 + ks * 32 + grp * 8]);
    for (int dt = 0; dt < 2; ++dt)
      for (int ks = 0; ks < 2; ++ks)
        vb[dt][ks] = *reinterpret_cast<const short8*>(&Vt[win][dt * 16 + l15][ks * 32 + grp * 8]);
    f32x4 o[2][2];
    for (int mt = 0; mt < 2; ++mt)
      for (int dt = 0; dt < 2; ++dt) o[mt][dt] = (f32x4){0, 0, 0, 0};
    for (int ks = 0; ks < 2; ++ks)
      for (int mt = 0; mt < 2; ++mt)
        for (int dt = 0; dt < 2; ++dt)
          o[mt][dt] = __builtin_amdgcn_mfma_f32_16x16x32_bf16(pa[mt][ks], vb[dt][ks], o[mt][dt], 0, 0, 0);

    // ---- ao (normalized, bf16) -> LDS (reuse P cols 80..111, own rows) ----
    for (int mt = 0; mt < 2; ++mt)
      for (int dt = 0; dt < 2; ++dt)
        for (int r = 0; r < 4; ++r) {
          int lr = sub * 32 + mt * 16 + grp * 4 + r;
          QK[win][lr][80 + dt * 16 + l15] = f2bf(o[mt][dt][r] * rinv[mt][r]);
        }

    // ---- proj accumulate: pacc += ao @ pw_h^T (K=32 slice) ----
    short8 aoa[2];
    for (int mt = 0; mt < 2; ++mt)
      aoa[mt] = *reinterpret_cast<const short8*>(&QK[win][sub * 32 + mt * 16 + l15][80 + grp * 8]);
    for (int nt = 0; nt < 8; ++nt) {
      short8 pbv = *reinterpret_cast<const short8*>(&pwbf[(size_t)(nt * 16 + l15) * 128 + h * 32 + grp * 8]);
      for (int mt = 0; mt < 2; ++mt)
        pacc[mt][nt] = __builtin_amdgcn_mfma_f32_16x16x32_bf16(aoa[mt], pbv, pacc[mt][nt], 0, 0, 0);
    }
    __syncthreads();   // protect q/k/Vt rewrite (next head) vs pair-wave reads
  }

  // ---- epilogue: + proj bias, write fp32 out (B,N,C) ----
  for (int mt = 0; mt < 2; ++mt)
    for (int r = 0; r < 4; ++r) {
      int lr = sub * 32 + mt * 16 + grp * 4 + r;
      if (lr < 49) {
        float* orow = &out[xbase + (size_t)lr * 128];
        for (int nt = 0; nt < 8; ++nt)
          orow[nt * 16 + l15] = pacc[mt][nt][r] + pb[nt * 16 + l15];
      }
    }
}

// ---------------------------------------------------------------------------
extern "C" void kernel_launch(void* const* d_in, const int* in_sizes, int n_in,
                              void* d_out, int out_size, void* d_ws, size_t ws_size,
                              hipStream_t stream) {
  const float* x    = (const float*)d_in[0];
  const float* mask = (const float*)d_in[1];
  const float* qkvw = (const float*)d_in[2];
  const float* qkvb = (const float*)d_in[3];
  const float* rpb  = (const float*)d_in[4];
  const float* pw   = (const float*)d_in[5];
  const float* pb   = (const float*)d_in[6];
  float* out = (float*)d_out;

  char* ws = (char*)d_ws;
  short* wbf  = (short*)ws;                 // 384*128 bf16 = 98,304 B
  short* pwbf = (short*)(ws + 98304);       // 128*128 bf16 = 32,768 B
  float* tab  = (float*)(ws + 131072);      // 64*4*49*49 fp32 = 2,458,624 B

  k_prep <<<264,  256, 0, stream>>>(mask, rpb, qkvw, pw, tab, wbf, pwbf);
  k_fused<<<2048, 256, 0, stream>>>(x, qkvb, pb, tab, wbf, pwbf, out);
}